// Round 6
// baseline (191.383 us; speedup 1.0000x reference)
//
#include <hip/hip_runtime.h>
#include <hip/hip_bf16.h>

// out[b, p, c, d, e] = sr * cos(phi[b]*p) - si * sin(phi[b]*p)
// B=8, C=40; p-stride C^3 = 64,000; batch stride C^4 = 2,560,000.
//
// R5 post-mortem: nontemporal loads+stores fixed the L3 dirty-writeback
// thrash (R2-R4's invariant 76-us wall); phase_apply now runs below the
// harness's 48.8-us fill kernels (which measure 6.7 TB/s achievable).
// R6: kill the block-granularity tail — 2500 coarse blocks left a 452-block
// second phase; SWEEPS=2 gives exactly 10,000 blocks (n4 = 5,120,000 = 512 *
// 10,000, no tail kernel), keeping 4 independent 16-B loads in flight per
// thread. Everything else identical.

#define NBATCH 8
#define CUTOFF 40
#define C3 (CUTOFF * CUTOFF * CUTOFF)          // 64000
#define C4 (C3 * CUTOFF)                       // 2560000
#define SWEEPS 2
#define GPB (SWEEPS * 256)                     // float4 groups per block = 512

typedef float v4f __attribute__((ext_vector_type(4)));

__global__ __launch_bounds__(256) void phase_apply(
    const float* __restrict__ phi,
    const float* __restrict__ sr,
    const float* __restrict__ si,
    float* __restrict__ out)
{
    int t = blockIdx.x * GPB + threadIdx.x;    // sweep-0 group index

    const v4f* re4 = (const v4f*)sr;
    const v4f* im4 = (const v4f*)si;
    v4f*       o4  = (v4f*)out;

    // Batch all loads, nontemporal: stream without displacing the harness's
    // dirty restore/poison lines in L3 (R5's confirmed win).
    v4f re[SWEEPS], im[SWEEPS];
#pragma unroll
    for (int k = 0; k < SWEEPS; ++k) {
        re[k] = __builtin_nontemporal_load(&re4[t + k * 256]);
        im[k] = __builtin_nontemporal_load(&im4[t + k * 256]);
    }

#pragma unroll
    for (int k = 0; k < SWEEPS; ++k) {
        int idx  = t + k * 256;
        int base = idx * 4;
        int b    = base / C4;
        int p    = (base - b * C4) / C3;
        // wave spans 256 consecutive elems; C3 % 256 == 0 -> (b,p) wave-uniform
        int bu = __builtin_amdgcn_readfirstlane(b);
        int pu = __builtin_amdgcn_readfirstlane(p);
        float s, c;
        sincosf(phi[bu] * (float)pu, &s, &c);   // ~2 sincos/thread: VALU noise
        v4f o = re[k] * c - im[k] * s;
        __builtin_nontemporal_store(o, &o4[idx]);
    }
}

// guarded tail (not hit for B=8, C=40: n4 % GPB == 0), kept for generality
__global__ __launch_bounds__(256) void phase_apply_tail(
    const float* __restrict__ phi,
    const float* __restrict__ sr,
    const float* __restrict__ si,
    float* __restrict__ out,
    int start, int n4)
{
    int idx = start + blockIdx.x * blockDim.x + threadIdx.x;
    if (idx >= n4) return;
    int base = idx * 4;
    int b    = base / C4;
    int p    = (base - b * C4) / C3;
    float s, c;
    sincosf(phi[b] * (float)p, &s, &c);
    const v4f re = ((const v4f*)sr)[idx];
    const v4f im = ((const v4f*)si)[idx];
    v4f o = re * c - im * s;
    ((v4f*)out)[idx] = o;
}

extern "C" void kernel_launch(void* const* d_in, const int* in_sizes, int n_in,
                              void* d_out, int out_size, void* d_ws, size_t ws_size,
                              hipStream_t stream) {
    const float* phi = (const float*)d_in[0];
    const float* sr  = (const float*)d_in[1];
    const float* si  = (const float*)d_in[2];
    float* out = (float*)d_out;

    int n  = in_sizes[1];                      // 20,480,000 complex elements
    int n4 = n / 4;                            // 5,120,000 float4 groups

    int nblocks = n4 / GPB;                    // 10,000 for this problem
    if (nblocks > 0)
        phase_apply<<<nblocks, 256, 0, stream>>>(phi, sr, si, out);

    int rem_start = nblocks * GPB;
    int rem = n4 - rem_start;
    if (rem > 0) {
        int grid = (rem + 255) / 256;
        phase_apply_tail<<<grid, 256, 0, stream>>>(phi, sr, si, out, rem_start, n4);
    }
}